// Round 6
// baseline (322.861 us; speedup 1.0000x reference)
//
#include <hip/hip_runtime.h>

// ROI Align (FPN multi-level), OUT=7, ratio=2.
// Round-10: cross-round analysis showed units-in-flight pinned at ~25 by LDS
// and a CU-shared pipe saturated at ~274 cy/unit, invariant to memory source
// (HBM vs L2) => global_load_lds request serialization (per-lane DMA) is the
// prime suspect. Fix: reg-staging via per-lane global_load_dwordx4 (coalesced
// TA path, ~55 line-req/unit) -> predicated ds_write_b128. Enables: no dump
// row, no buffer-overhang safe-term (per-lane row clamp), paired ds_read2_b32
// taps (16->8 DS ops), 18.4KB LDS/block -> 8 blocks/CU -> 32 units in flight.
// Keeps R4's proven structure: 2 channels of one ROI per wave-shot, c-major
// XCD channel-pair chunking (FETCH 77MB, L2/L3-resident), geometry tables.
// Unsafe (oversize) ROIs -> compacted list -> global-gather fallback kernel.

#define NCH 256
#define POOL 7
#define NBIN 49
#define CAP 1152          // floats per unit footprint region
#define WPB 2             // main-kernel waves per block (128 threads)
#define PWPB 4            // precompute waves per block
#define TS 160            // u32 words per ROI table entry (640 B)
#define ITMAX 5           // max staging iterations (safe path)

typedef float f4g __attribute__((ext_vector_type(4), aligned(4)));   // global
typedef float f4l __attribute__((ext_vector_type(4), aligned(16)));  // LDS
#define RFL(x) __builtin_amdgcn_readfirstlane(x)

// ---------------------------------------------------------------------------
// Per-ROI precompute: one wave per ROI. tab[m*TS..]:
//  [0] base_off (elems,c=0) [1] lvl   [2] HW   [3] W
//  [4] lpr  [5] Mg=ceil(2^16/lpr)  [6] rpi=64/lpr  [7] iters
//  [8] gstep=rpi*W  [9] (unused)  [10] (FH-1)*W  [11] safe
//  [12] FW  [13] RS4  [14] (unused)  [15] (unused)
//  [16..71]  xtab[14] uint4 {xr, xp=min(xr+1,FW-1), wxl, wxh}
//  [72..127] ytab[14] uint4 {(ylo-ry0)*RS4, (yhi-ry0)*RS4, wyl, wyh}
//  [128..155] ytabW[14] uint2 {(ylo-ry0)*W, (yhi-ry0)*W}   (global-gather)
// Unsafe ROIs appended to list[] via atomic count.
// ---------------------------------------------------------------------------
__global__ __launch_bounds__(256) void roi_precompute_kernel(
    const float* __restrict__ boxes, const int* __restrict__ bidx,
    unsigned int* __restrict__ tab, unsigned int* __restrict__ list,
    unsigned int* __restrict__ cnt, int M)
{
    const int lane = threadIdx.x & 63;
    const int m = blockIdx.x * PWPB + (threadIdx.x >> 6);
    if (m >= M) return;

    float bx0 = boxes[4 * m + 0];
    float by0 = boxes[4 * m + 1];
    float bx1 = boxes[4 * m + 2];
    float by1 = boxes[4 * m + 3];

    float area = (bx1 - bx0) * (by1 - by0);
    float sz   = sqrtf(area);
    float lvlf = floorf(4.0f + log2f(sz / 224.0f + 1e-8f));
    lvlf = fminf(fmaxf(lvlf, 2.0f), 5.0f);
    int lvl = (int)lvlf - 2;

    int H, W; float scale;
    if (lvl == 0)      { H = 200; W = 304; scale = 0.25f;    }
    else if (lvl == 1) { H = 100; W = 152; scale = 0.125f;   }
    else if (lvl == 2) { H = 50;  W = 76;  scale = 0.0625f;  }
    else               { H = 25;  W = 38;  scale = 0.03125f; }

    float x0 = bx0 * scale - 0.5f;
    float y0 = by0 * scale - 0.5f;
    float bin_w = (bx1 * scale - 0.5f - x0) * (1.0f / 7.0f);
    float bin_h = (by1 * scale - 0.5f - y0) * (1.0f / 7.0f);

    // lanes 0..13: x samples; lanes 14..27: y samples
    int axis = lane >= 14;
    int s    = axis ? (lane - 14) : lane;
    float off = (float)(s >> 1) + ((s & 1) ? 0.75f : 0.25f);
    float cv    = axis ? (y0 + bin_h * off) : (x0 + bin_w * off);
    float size  = axis ? (float)H : (float)W;
    float valid = (cv >= -1.0f && cv <= size) ? 1.0f : 0.0f;
    float cc    = fmaxf(cv, 0.0f);
    float lo_f  = floorf(cc);
    bool  capd  = lo_f >= size - 1.0f;
    int   lo    = capd ? (int)size - 1 : (int)lo_f;
    int   hi    = capd ? lo : lo + 1;
    float l     = capd ? 0.0f : (cc - lo_f);
    float wlo   = (1.0f - l) * valid;
    float whi   = l * valid;

    int rx0 = __shfl(lo, 0);
    int rxe = __shfl(hi, 13);
    int ry0 = __shfl(lo, 14);
    int rye = __shfl(hi, 27);

    int FW  = rxe - rx0 + 1;
    int FH  = rye - ry0 + 1;
    int lpr = (FW + 3) >> 2;
    int RS4 = lpr << 2;
    int rpi = 64 / lpr;
    int iters = (FH + rpi - 1) / rpi;
    unsigned Mg  = (65536u + (unsigned)lpr - 1u) / (unsigned)lpr;
    unsigned HW  = (unsigned)(H * W);
    unsigned base_off = (unsigned)bidx[m] * 256u * HW
                      + (unsigned)ry0 * (unsigned)W + (unsigned)rx0;
    // safe: padded write extent fits CAP; bounded iteration count; row
    // windows (RS4 <= W) can never cross the channel-plane row end, so no
    // buffer-overhang condition is needed (per-lane row clamp in kernel).
    int safe = (iters * rpi * RS4 <= CAP)
            && (iters <= ITMAX)
            && (FW <= W - 4);

    unsigned* t = tab + (size_t)m * TS;
    if (lane == 0) {
        t[0]  = base_off;
        t[1]  = (unsigned)lvl;
        t[2]  = HW;
        t[3]  = (unsigned)W;
        t[4]  = (unsigned)lpr;
        t[5]  = Mg;
        t[6]  = (unsigned)rpi;
        t[7]  = (unsigned)iters;
        t[8]  = (unsigned)(rpi * W);
        t[9]  = 0u;
        t[10] = (unsigned)((FH - 1) * W);
        t[11] = (unsigned)safe;
        t[12] = (unsigned)FW;
        t[13] = (unsigned)RS4;
        t[14] = 0u;
        t[15] = 0u;
        if (!safe) {
            unsigned i = atomicAdd(cnt, 1u);
            list[i] = (unsigned)m;
        }
    }
    if (lane < 28) {
        if (!axis) {
            int xr = lo - rx0;
            int xp = min(xr + 1, FW - 1);   // for fallback kernel only
            uint4 v;
            v.x = (unsigned)xr;
            v.y = (unsigned)xp;
            v.z = __float_as_uint(wlo);
            v.w = __float_as_uint(whi);
            *(uint4*)(t + 16 + 4 * s) = v;
        } else {
            uint4 v;
            v.x = (unsigned)((lo - ry0) * RS4);
            v.y = (unsigned)((hi - ry0) * RS4);
            v.z = __float_as_uint(wlo);
            v.w = __float_as_uint(whi);
            *(uint4*)(t + 72 + 4 * s) = v;
            uint2 vw;
            vw.x = (unsigned)((lo - ry0) * W);
            vw.y = (unsigned)((hi - ry0) * W);
            *(uint2*)(t + 128 + 2 * s) = vw;
        }
    }
}

// ---------------------------------------------------------------------------
// Main kernel: 2 channels of one ROI per wave, reg-staged footprints,
// c-major order with XCD channel-pair chunking.
// ---------------------------------------------------------------------------
__global__ __launch_bounds__(128, 4) void roi_align_kernel(
    const float* __restrict__ f0, const float* __restrict__ f1,
    const float* __restrict__ f2, const float* __restrict__ f3,
    const unsigned int* __restrict__ tab,
    float* __restrict__ out, int M)
{
    __shared__ float sF[WPB][2 * CAP];

    const int lane = threadIdx.x & 63;
    const int w    = __builtin_amdgcn_readfirstlane(threadIdx.x >> 6);

    // grid = mblocks * 128 (divisible by 8)
    const unsigned mblocks = (unsigned)gridDim.x >> 7;
    const unsigned rb    = blockIdx.x;
    const unsigned xcd   = rb & 7u;
    const unsigned idx   = rb >> 3;                // 0 .. mblocks*16-1
    const unsigned cpblk = idx / mblocks;          // 0..15
    const unsigned mb    = idx - cpblk * mblocks;
    const int c0 = (int)((xcd * 16u + cpblk) * 2u);
    const int m  = (int)(mb * WPB) + w;
    if (m >= M) return;

    const unsigned* t = tab + (size_t)m * TS;

    // ---- per-lane geometry (shared by both units) ----
    const int ci = lane < NBIN ? lane : 0;
    const int py = ci / POOL;
    const int px = ci - POOL * py;
    const uint4* xt = (const uint4*)(t + 16);
    const uint4* yt = (const uint4*)(t + 72);
    const uint4 X0 = xt[2 * px];
    const uint4 X1 = xt[2 * px + 1];
    const uint4 Y0 = yt[2 * py];
    const uint4 Y1 = yt[2 * py + 1];

    // ---- wave-uniform staging scalars ----
    const uint4 s0 = *(const uint4*)(t);           // base_off, lvl, HW, W
    const uint4 s1 = *(const uint4*)(t + 4);       // lpr, Mg, rpi, iters
    const uint4 s2 = *(const uint4*)(t + 8);       // gstep, -, fhw, safe

    const int safe = RFL((int)s2.w);
    if (!safe) return;                             // fallback kernel covers

    const int lvl = RFL((int)s0.y);
    const float* fp = (lvl == 0) ? f0 : (lvl == 1) ? f1 : (lvl == 2) ? f2 : f3;
    const unsigned HW = s0.z;
    const unsigned Wd = s0.w;
    const unsigned baseA = s0.x + (unsigned)c0 * HW;

    const int lpr      = RFL((int)s1.x);
    const unsigned Mg  = s1.y;
    const int rpi      = RFL((int)s1.z);
    const int iters    = RFL((int)s1.w);
    const unsigned gstep = s2.x;                   // rpi*W elems
    const unsigned fhw   = s2.z;                   // (FH-1)*W elems
    const int RS4 = lpr << 2;

    const int sfy  = (int)(((unsigned)lane * Mg) >> 16);   // lane/lpr exact
    const int sfx4 = (lane - sfy * lpr) << 2;
    const bool act = sfy < rpi;

    // ---- stage: per-lane coalesced dwordx4 loads -> regs ----
    f4g a[ITMAX], b[ITMAX];
    {
        unsigned off = baseA + (unsigned)sfy * Wd + (unsigned)sfx4;
        const unsigned ocap = baseA + fhw + (unsigned)sfx4;  // pad rows reload
        #pragma unroll
        for (int it = 0; it < ITMAX; ++it) {
            if (act && it < iters) {
                unsigned o = off < ocap ? off : ocap;
                a[it] = *(const f4g*)(fp + o);
                b[it] = *(const f4g*)(fp + o + HW);
            }
            off += gstep;
        }
    }
    // ---- write regs -> LDS (predicated b128; compiler inserts waits) ----
    {
        float* LA = &sF[w][0];
        unsigned lo = (unsigned)sfy * (unsigned)RS4 + (unsigned)sfx4;
        const unsigned lstep = (unsigned)(rpi * RS4);
        #pragma unroll
        for (int it = 0; it < ITMAX; ++it) {
            if (act && it < iters) {
                *(f4l*)(LA + lo)       = a[it];
                *(f4l*)(LA + CAP + lo) = b[it];
            }
            lo += lstep;
        }
    }

    // ---- compute 49 bins x 2 units (adjacent-tap pairs -> ds_read2) ----
    {
        const float* FbA = &sF[w][0];
        const float* FbB = &sF[w][CAP];
        const unsigned xA = X0.x, xB = X1.x;       // xr0, xr1
        const float wxl0 = __uint_as_float(X0.z), wxh0 = __uint_as_float(X0.w);
        const float wxl1 = __uint_as_float(X1.z), wxh1 = __uint_as_float(X1.w);
        const unsigned ra = Y0.x, rb2 = Y0.y, rc = Y1.x, rd = Y1.y;
        const float wy0 = __uint_as_float(Y0.z), wy1 = __uint_as_float(Y0.w);
        const float wy2 = __uint_as_float(Y1.z), wy3 = __uint_as_float(Y1.w);
        // note: [x+1] at x-cap reads a written-but-unused col; weight is
        // exactly 0 and staged data is finite, so the product is 0.

        const float* r0 = FbA + ra;
        const float* r1 = FbA + rb2;
        const float* r2 = FbA + rc;
        const float* r3 = FbA + rd;
        float a0 = r0[xA] * wxl0 + r0[xA + 1] * wxh0
                 + r0[xB] * wxl1 + r0[xB + 1] * wxh1;
        float a1 = r1[xA] * wxl0 + r1[xA + 1] * wxh0
                 + r1[xB] * wxl1 + r1[xB + 1] * wxh1;
        float a2 = r2[xA] * wxl0 + r2[xA + 1] * wxh0
                 + r2[xB] * wxl1 + r2[xB + 1] * wxh1;
        float a3 = r3[xA] * wxl0 + r3[xA + 1] * wxh0
                 + r3[xB] * wxl1 + r3[xB + 1] * wxh1;
        float accA = wy0 * a0 + wy1 * a1 + wy2 * a2 + wy3 * a3;

        const float* q0 = FbB + ra;
        const float* q1 = FbB + rb2;
        const float* q2 = FbB + rc;
        const float* q3 = FbB + rd;
        float b0 = q0[xA] * wxl0 + q0[xA + 1] * wxh0
                 + q0[xB] * wxl1 + q0[xB + 1] * wxh1;
        float b1 = q1[xA] * wxl0 + q1[xA + 1] * wxh0
                 + q1[xB] * wxl1 + q1[xB + 1] * wxh1;
        float b2 = q2[xA] * wxl0 + q2[xA + 1] * wxh0
                 + q2[xB] * wxl1 + q2[xB + 1] * wxh1;
        float b3 = q3[xA] * wxl0 + q3[xA + 1] * wxh0
                 + q3[xB] * wxl1 + q3[xB + 1] * wxh1;
        float accB = wy0 * b0 + wy1 * b1 + wy2 * b2 + wy3 * b3;

        if (lane < NBIN) {
            size_t ob = ((size_t)m * NCH + (unsigned)c0) * NBIN
                      + (unsigned)lane;
            out[ob]        = accA * 0.25f;
            out[ob + NBIN] = accB * 0.25f;
        }
    }
}

// ---------------------------------------------------------------------------
// Fallback: unsafe (oversize) ROIs via compacted list, direct global gather.
// ---------------------------------------------------------------------------
__global__ __launch_bounds__(256) void roi_fallback_kernel(
    const float* __restrict__ f0, const float* __restrict__ f1,
    const float* __restrict__ f2, const float* __restrict__ f3,
    const unsigned int* __restrict__ tab, const unsigned int* __restrict__ list,
    const unsigned int* __restrict__ cnt,
    float* __restrict__ out, int M)
{
    const int lane = threadIdx.x & 63;
    const unsigned wv = blockIdx.x * 4u + (threadIdx.x >> 6);
    const unsigned nw = gridDim.x * 4u;
    const unsigned total = cnt[0] * 256u;

    const int ci = lane < NBIN ? lane : 0;
    const int py = ci / POOL;
    const int px = ci - POOL * py;

    for (unsigned u = wv; u < total; u += nw) {
        const unsigned mi = list[u >> 8];
        const unsigned c  = u & 255u;
        const unsigned* t = tab + (size_t)mi * TS;

        const uint4 s0 = *(const uint4*)(t);
        const int lvl = (int)s0.y;
        const float* fp = (lvl == 0) ? f0 : (lvl == 1) ? f1
                        : (lvl == 2) ? f2 : f3;
        const float* src = fp + (size_t)(s0.x + c * s0.z);

        const uint4* xt = (const uint4*)(t + 16);
        const uint4* yt = (const uint4*)(t + 72);
        const uint2* yw = (const uint2*)(t + 128);
        const uint4 X0 = xt[2 * px];
        const uint4 X1 = xt[2 * px + 1];
        const uint4 Y0 = yt[2 * py];
        const uint4 Y1 = yt[2 * py + 1];
        const uint2 W0 = yw[2 * py];
        const uint2 W1 = yw[2 * py + 1];

        const unsigned xr0 = X0.x, xp0 = X0.y, xr1 = X1.x, xp1 = X1.y;
        const float wxl0 = __uint_as_float(X0.z), wxh0 = __uint_as_float(X0.w);
        const float wxl1 = __uint_as_float(X1.z), wxh1 = __uint_as_float(X1.w);
        const unsigned ra = W0.x, rb = W0.y, rc = W1.x, rd = W1.y;
        const float wy0 = __uint_as_float(Y0.z), wy1 = __uint_as_float(Y0.w);
        const float wy2 = __uint_as_float(Y1.z), wy3 = __uint_as_float(Y1.w);

        float a0 = src[ra + xr0] * wxl0 + src[ra + xp0] * wxh0
                 + src[ra + xr1] * wxl1 + src[ra + xp1] * wxh1;
        float a1 = src[rb + xr0] * wxl0 + src[rb + xp0] * wxh0
                 + src[rb + xr1] * wxl1 + src[rb + xp1] * wxh1;
        float a2 = src[rc + xr0] * wxl0 + src[rc + xp0] * wxh0
                 + src[rc + xr1] * wxl1 + src[rc + xp1] * wxh1;
        float a3 = src[rd + xr0] * wxl0 + src[rd + xp0] * wxh0
                 + src[rd + xr1] * wxl1 + src[rd + xp1] * wxh1;
        float acc = wy0 * a0 + wy1 * a1 + wy2 * a2 + wy3 * a3;

        if (lane < NBIN) {
            size_t ob = ((size_t)mi * NCH + c) * NBIN + (unsigned)lane;
            out[ob] = acc * 0.25f;
        }
    }
}

extern "C" void kernel_launch(void* const* d_in, const int* in_sizes, int n_in,
                              void* d_out, int out_size, void* d_ws, size_t ws_size,
                              hipStream_t stream) {
    const float* f0    = (const float*)d_in[0];
    const float* f1    = (const float*)d_in[1];
    const float* f2    = (const float*)d_in[2];
    const float* f3    = (const float*)d_in[3];
    const float* boxes = (const float*)d_in[4];
    const int*   bidx  = (const int*)d_in[5];
    float* out = (float*)d_out;

    int M = in_sizes[4] / 4;
    unsigned int* cnt  = (unsigned int*)d_ws;
    unsigned int* list = cnt + 64;                    // up to 8192 ROIs
    unsigned int* tab  = cnt + 64 + 8192;             // M * 640 B

    hipMemsetAsync(d_ws, 0, 4, stream);

    int pblocks = (M + PWPB - 1) / PWPB;
    hipLaunchKernelGGL(roi_precompute_kernel, dim3(pblocks), dim3(256), 0,
                       stream, boxes, bidx, tab, list, cnt, M);

    int mblocks = (M + WPB - 1) / WPB;
    int blocks = mblocks * (NCH / 2);                 // 2 channels per wave
    hipLaunchKernelGGL(roi_align_kernel, dim3(blocks), dim3(128), 0, stream,
                       f0, f1, f2, f3, tab, out, M);

    hipLaunchKernelGGL(roi_fallback_kernel, dim3(128), dim3(256), 0, stream,
                       f0, f1, f2, f3, tab, list, cnt, out, M);
}